// Round 1
// 95.158 us; speedup vs baseline: 1.0220x; 1.0220x over previous
//
#include <hip/hip_runtime.h>
#include <hip/hip_bf16.h>

#define IN_F   1024
#define OUT_F  64
#define INTER  32
#define BATCH  512
#define NCOL   2048              // OUT_F * INTER
#define OUT_W  1088              // IN_F + OUT_F
#define SCREEN_T 25.0f           // drop terms with dist>=25: error <= 512*e^-25 ~ 7e-9
#define LIST_CAP 2048

typedef short bf16x8 __attribute__((ext_vector_type(8)));  // 8 bf16 (4 VGPRs)
typedef float f32x4  __attribute__((ext_vector_type(4)));  // 4 fp32

__device__ __forceinline__ unsigned short f2bf(float v) {
    __hip_bfloat16 h = __float2bfloat16(v);
    return *reinterpret_cast<unsigned short*>(&h);
}

// ---------------- Prep: copy x -> out, init feature cols to 1.0 (diagonal term),
//                  cast x -> xb, transpose T -> Bt ----------------
__global__ __launch_bounds__(256) void prep_kernel(const float* __restrict__ x,
                                                   const float* __restrict__ T,
                                                   float* __restrict__ out,
                                                   unsigned short* __restrict__ xb,
                                                   unsigned short* __restrict__ Bt) {
    const int tid = threadIdx.x;
    if (blockIdx.x < BATCH) {
        const int r = blockIdx.x;
        const float4 v = ((const float4*)(x + (size_t)r * IN_F))[tid];
        *(float4*)(out + (size_t)r * OUT_W + tid * 4) = v;
        unsigned short h[4] = {f2bf(v.x), f2bf(v.y), f2bf(v.z), f2bf(v.w)};
        *(uint2*)(xb + (size_t)r * IN_F + tid * 4) = *(uint2*)h;
        if (tid < OUT_F / 4)   // exp(0)=1 self-term baked in; screen adds rare survivors only
            *(float4*)(out + (size_t)r * OUT_W + IN_F + tid * 4) = make_float4(1.f, 1.f, 1.f, 1.f);
    } else {
        __shared__ unsigned short ldsT[64][72];   // [n][k], row stride 144B (16B-aligned)
        const int bid = blockIdx.x - BATCH;
        const int n0 = (bid & 31) * 64;
        const int k0 = (bid >> 5) * 64;
        const int nl = tid & 63;
        const int kc = (tid >> 6) * 16;
        unsigned short u[16];
        #pragma unroll
        for (int j = 0; j < 16; ++j)
            u[j] = f2bf(T[(size_t)(k0 + kc + j) * NCOL + n0 + nl]);
        *(uint4*)&ldsT[nl][kc]     = *(uint4*)&u[0];
        *(uint4*)&ldsT[nl][kc + 8] = *(uint4*)&u[8];
        __syncthreads();
        const int n2  = tid >> 2;
        const int kc2 = (tid & 3) * 16;
        uint4 a = *(uint4*)&ldsT[n2][kc2];
        uint4 b = *(uint4*)&ldsT[n2][kc2 + 8];
        unsigned short* dst = Bt + (size_t)(n0 + n2) * IN_F + k0 + kc2;
        *(uint4*)dst       = a;
        *(uint4*)(dst + 8) = b;
    }
}

// ---------------- GEMM (bf16 MFMA, no LDS, no barriers), Mt f32 + fused quarter-sums ----------------
// R0 fusion: each wave holds a full 16(batch) x 32(inter) tile for one o in acc regs,
// so the quarter-sums s[o][b][q] (8-k octet sums) are an 8-lane-aligned __shfl_xor
// reduction (lr 0-7 = octet 0, lr 8-15 = octet 1; acc1 gives octets 2,3).
// Kills the separate sums_kernel (one dispatch + 4MB Mt re-read + 0.5MB s round-trip).
__global__ __launch_bounds__(256) void gemm_kernel(const unsigned short* __restrict__ xb,
                                                   const unsigned short* __restrict__ Bt,
                                                   float* __restrict__ Mt,
                                                   float* __restrict__ s) {
    const int tid  = threadIdx.x;
    const int wave = tid >> 6, lane = tid & 63;
    const int quad = lane >> 4, lr = lane & 15;
    const int m0 = (blockIdx.y * 4 + wave) * 16;
    const int n0 = blockIdx.x * 32;

    const unsigned short* pA  = xb + (size_t)(m0 + lr) * IN_F + quad * 8;
    const unsigned short* pB0 = Bt + (size_t)(n0 + lr) * IN_F + quad * 8;
    const unsigned short* pB1 = pB0 + 16 * IN_F;

    f32x4 acc0 = {0.f, 0.f, 0.f, 0.f};
    f32x4 acc1 = {0.f, 0.f, 0.f, 0.f};
    #pragma unroll 8
    for (int k0 = 0; k0 < IN_F; k0 += 32) {
        bf16x8 a  = *(const bf16x8*)(pA + k0);
        bf16x8 b0 = *(const bf16x8*)(pB0 + k0);
        bf16x8 b1 = *(const bf16x8*)(pB1 + k0);
        acc0 = __builtin_amdgcn_mfma_f32_16x16x32_bf16(a, b0, acc0, 0, 0, 0);
        acc1 = __builtin_amdgcn_mfma_f32_16x16x32_bf16(a, b1, acc1, 0, 0, 0);
    }
    // C/D: col = lane&15, row = quad*4 + r. Output Mt[o][b][k].
    float* base = Mt + (size_t)(n0 >> 5) * (BATCH * INTER) + (size_t)(m0 + quad * 4) * INTER;
    #pragma unroll
    for (int r = 0; r < 4; ++r) {
        base[r * INTER + lr]      = acc0[r];
        base[r * INTER + 16 + lr] = acc1[r];
    }
    // Fused quarter sums: s[o][b][q], q = k-octet. 8-lane groups are lr-octets.
    #pragma unroll
    for (int r = 0; r < 4; ++r) {
        float r0 = acc0[r], r1 = acc1[r];
        r0 += __shfl_xor(r0, 1); r0 += __shfl_xor(r0, 2); r0 += __shfl_xor(r0, 4);
        r1 += __shfl_xor(r1, 1); r1 += __shfl_xor(r1, 2); r1 += __shfl_xor(r1, 4);
        if ((lane & 7) == 0) {
            const int b  = m0 + quad * 4 + r;
            const int qq = (lane >> 3) & 1;        // lr 0-7 -> 0, lr 8-15 -> 1
            float* sb = s + ((size_t)(n0 >> 5) * BATCH + b) * 4;
            sb[qq]     = r0;                        // octets 0/1 (k 0..15)
            sb[2 + qq] = r1;                        // octets 2/3 (k 16..31)
        }
    }
}

// ---------------- Branchless screen + survivor list ----------------
// dist >= L = sum_q |s_a,q - s_b,q|. L >= T => term dropped (error <= 512e^-25).
// R13 post-mortem: inline `if` body made the loop latency/branch-bound (VALUBusy 14%).
// Now: loop body = ds_read + 7 VALU + cmp; survivors (expected ~0; diagonal excluded,
// handled as the 1.0 init in prep) append to an LDS list processed after the loop.
// grid (8 ac, 64 o, 2 bs), block 256: a in [ac*64,+64), b in [bs*256,+256), wave w
// covers 64 b's. 1024 blocks = 4/CU = 16 waves/CU.
__global__ __launch_bounds__(256, 4) void screen_kernel(const float* __restrict__ Mt,
                                                        const float* __restrict__ s,
                                                        float* __restrict__ out) {
    const int o    = blockIdx.y;
    const int ac   = blockIdx.x;
    const int bs   = blockIdx.z;
    const int tid  = threadIdx.x;
    const int lane = tid & 63;
    const int wave = tid >> 6;
    const int a    = ac * 64 + lane;
    const float* slabM = Mt + (size_t)o * (BATCH * INTER);
    const float* slabS = s + (size_t)o * (BATCH * 4);

    __shared__ float4 s_lds[256];        // 4 KB: the block's 256 b quarter-sum vectors
    __shared__ unsigned int list[LIST_CAP];
    __shared__ int cnt;
    s_lds[tid] = ((const float4*)slabS)[bs * 256 + tid];
    if (tid == 0) cnt = 0;

    const float4 sa = ((const float4*)slabS)[a];   // coalesced global
    __syncthreads();

    const int b0 = bs * 256 + wave * 64;
    #pragma unroll 8
    for (int j = 0; j < 64; ++j) {
        const float4 sb = s_lds[wave * 64 + j];    // ds_read_b128, wave-uniform broadcast
        const float L = fabsf(sa.x - sb.x) + fabsf(sa.y - sb.y)
                      + fabsf(sa.z - sb.z) + fabsf(sa.w - sb.w);
        const int b = b0 + j;
        if (L < SCREEN_T && b != a) {              // ~never taken: append only
            const int idx = atomicAdd(&cnt, 1);
            if (idx < LIST_CAP) list[idx] = ((unsigned)lane << 16) | (unsigned)b;
        }
    }
    __syncthreads();

    const int n = min(cnt, LIST_CAP);
    for (int i = tid; i < n; i += 256) {           // expected n == 0
        const unsigned v = list[i];
        const int aa = ac * 64 + (int)(v >> 16);
        const int bb = (int)(v & 0xffffu);
        const float* pa = slabM + (size_t)aa * INTER;
        const float* pb = slabM + (size_t)bb * INTER;
        float d0 = 0.f, d1 = 0.f, d2 = 0.f, d3 = 0.f;
        #pragma unroll
        for (int k = 0; k < INTER; k += 4) {
            const float4 va = *(const float4*)(pa + k);
            const float4 vb = *(const float4*)(pb + k);
            d0 += fabsf(va.x - vb.x);
            d1 += fabsf(va.y - vb.y);
            d2 += fabsf(va.z - vb.z);
            d3 += fabsf(va.w - vb.w);
        }
        atomicAdd(&out[(size_t)aa * OUT_W + IN_F + o], __expf(-((d0 + d1) + (d2 + d3))));
    }
}

extern "C" void kernel_launch(void* const* d_in, const int* in_sizes, int n_in,
                              void* d_out, int out_size, void* d_ws, size_t ws_size,
                              hipStream_t stream) {
    const float* x = (const float*)d_in[0];   // [512,1024] fp32
    const float* T = (const float*)d_in[1];   // [1024,2048] fp32 row-major (k-major)
    float* out = (float*)d_out;               // [512,1088] fp32

    // ws layout: xb (1MB) | Bt (4MB) | Mt (4MB f32) | s (512KB) = 9.5MB
    unsigned short* xb = (unsigned short*)d_ws;                          // [512][1024] bf16
    unsigned short* Bt = (unsigned short*)((char*)d_ws + (1u << 20));    // [2048][1024] bf16
    float*          Mt = (float*)((char*)d_ws + (5u << 20));             // [64][512][32] f32
    float*          s  = (float*)((char*)d_ws + (9u << 20));             // [64][512][4] f32

    prep_kernel<<<1024, 256, 0, stream>>>(x, T, out, xb, Bt);

    dim3 ggrid(NCOL / 32, BATCH / 64);        // 64 x 8 = 512 blocks
    gemm_kernel<<<ggrid, 256, 0, stream>>>(xb, Bt, Mt, s);

    dim3 sgrid(BATCH / 64, OUT_F, 2);         // 1024 blocks, 4/CU
    screen_kernel<<<sgrid, 256, 0, stream>>>(Mt, s, out);
}

// Round 3
// 81.669 us; speedup vs baseline: 1.1908x; 1.1652x over previous
//
#include <hip/hip_runtime.h>
#include <hip/hip_bf16.h>

#define IN_F   1024
#define OUT_F  64
#define INTER  32
#define BATCH  512
#define NCOL   2048              // OUT_F * INTER
#define OUT_W  1088              // IN_F + OUT_F
#define SCREEN_T 25.0f           // drop terms with dist>=25: error <= 512*e^-25 ~ 7e-9
#define LIST_CAP 2048

typedef short bf16x8 __attribute__((ext_vector_type(8)));  // 8 bf16 (4 VGPRs)
typedef float f32x4  __attribute__((ext_vector_type(4)));  // 4 fp32

__device__ __forceinline__ unsigned short f2bf(float v) {
    __hip_bfloat16 h = __float2bfloat16(v);
    return *reinterpret_cast<unsigned short*>(&h);
}

// ---------------- Prep: copy x -> out, init feature cols to 1.0 (diagonal term),
//                  cast x -> xb, transpose T -> Bt ----------------
__global__ __launch_bounds__(256) void prep_kernel(const float* __restrict__ x,
                                                   const float* __restrict__ T,
                                                   float* __restrict__ out,
                                                   unsigned short* __restrict__ xb,
                                                   unsigned short* __restrict__ Bt) {
    const int tid = threadIdx.x;
    if (blockIdx.x < BATCH) {
        const int r = blockIdx.x;
        const float4 v = ((const float4*)(x + (size_t)r * IN_F))[tid];
        *(float4*)(out + (size_t)r * OUT_W + tid * 4) = v;
        unsigned short h[4] = {f2bf(v.x), f2bf(v.y), f2bf(v.z), f2bf(v.w)};
        *(uint2*)(xb + (size_t)r * IN_F + tid * 4) = *(uint2*)h;
        if (tid < OUT_F / 4)   // exp(0)=1 self-term baked in; screen adds rare survivors only
            *(float4*)(out + (size_t)r * OUT_W + IN_F + tid * 4) = make_float4(1.f, 1.f, 1.f, 1.f);
    } else {
        __shared__ unsigned short ldsT[64][72];   // [n][k], row stride 144B (16B-aligned)
        const int bid = blockIdx.x - BATCH;
        const int n0 = (bid & 31) * 64;
        const int k0 = (bid >> 5) * 64;
        const int nl = tid & 63;
        const int kc = (tid >> 6) * 16;
        unsigned short u[16];
        #pragma unroll
        for (int j = 0; j < 16; ++j)
            u[j] = f2bf(T[(size_t)(k0 + kc + j) * NCOL + n0 + nl]);
        *(uint4*)&ldsT[nl][kc]     = *(uint4*)&u[0];
        *(uint4*)&ldsT[nl][kc + 8] = *(uint4*)&u[8];
        __syncthreads();
        const int n2  = tid >> 2;
        const int kc2 = (tid & 3) * 16;
        uint4 a = *(uint4*)&ldsT[n2][kc2];
        uint4 b = *(uint4*)&ldsT[n2][kc2 + 8];
        unsigned short* dst = Bt + (size_t)(n0 + n2) * IN_F + k0 + kc2;
        *(uint4*)dst       = a;
        *(uint4*)(dst + 8) = b;
    }
}

// ---------------- GEMM (bf16 MFMA), B-tile LDS-staged, Mt f32 + fused quarter-sums ----------------
// R1: 8-wave blocks (512 thr), grid (64 n-tiles, 4 m-tiles) = 256 blocks = 1/CU.
// Previous 4-wave version had every wave streaming the same 64 KB B-tile from L2
// (tile > 32 KB L1 => 4x redundant L2 traffic, ~768 KB/CU => ~5 us, vs 1.0 us MFMA floor).
// Now: B-tile staged ONCE into 64 KB LDS, shared by 8 waves; per-CU L2 bytes 768->320 KB.
// XOR swizzle (byte ^= (row&7)<<4): fragment ds_read_b128 has lanes lr=0..15 at row
// stride 2048 B (bank-invariant), so banks were 16*quad only (4 slots for 64 lanes);
// XOR makes slot = quad^(lr&7) -> uniform 8 lanes/slot = conflict-free-optimal for b128.
__global__ __launch_bounds__(512) void gemm_kernel(const unsigned short* __restrict__ xb,
                                                   const unsigned short* __restrict__ Bt,
                                                   float* __restrict__ Mt,
                                                   float* __restrict__ s) {
    __shared__ unsigned short Blds[32 * 1024];   // 64 KB: rows n0..n0+32, full K, swizzled
    const int tid  = threadIdx.x;                // 0..511
    const int wave = tid >> 6, lane = tid & 63;
    const int quad = lane >> 4, lr = lane & 15;
    const int m0 = (blockIdx.y * 8 + wave) * 16;
    const int n0 = blockIdx.x * 32;

    // Stage B-tile: 64 KB contiguous global (32 rows x 2 KB) -> swizzled LDS.
    {
        const uint4* src = (const uint4*)(Bt + (size_t)n0 * IN_F);
        uint4* dst = (uint4*)Blds;
        #pragma unroll
        for (int i = 0; i < 8; ++i) {
            const int idx  = i * 512 + tid;          // 16B units, coalesced
            const int byte = idx << 4;
            const int row  = byte >> 11;             // 2 KB per row
            const int sw   = byte ^ ((row & 7) << 4);
            dst[sw >> 4] = src[idx];
        }
    }

    const unsigned short* pA = xb + (size_t)(m0 + lr) * IN_F + quad * 8;
    const int cb  = quad * 16;                       // column byte base within row
    const int swx = ((lr & 7) << 4);                 // row-XOR (same for lr, lr+8, lr+16..)
    __syncthreads();

    f32x4 acc0 = {0.f, 0.f, 0.f, 0.f};
    f32x4 acc1 = {0.f, 0.f, 0.f, 0.f};
    #pragma unroll 8
    for (int k0 = 0; k0 < IN_F; k0 += 32) {
        bf16x8 a  = *(const bf16x8*)(pA + k0);
        const int sw0 = (lr * 2048 + cb + k0 * 2) ^ swx;
        bf16x8 b0 = *(const bf16x8*)((const char*)Blds + sw0);
        bf16x8 b1 = *(const bf16x8*)((const char*)Blds + sw0 + 32768);  // row+16: same row&7
        acc0 = __builtin_amdgcn_mfma_f32_16x16x32_bf16(a, b0, acc0, 0, 0, 0);
        acc1 = __builtin_amdgcn_mfma_f32_16x16x32_bf16(a, b1, acc1, 0, 0, 0);
    }
    // C/D: col = lane&15, row = quad*4 + r. Output Mt[o][b][k].
    float* base = Mt + (size_t)(n0 >> 5) * (BATCH * INTER) + (size_t)(m0 + quad * 4) * INTER;
    #pragma unroll
    for (int r = 0; r < 4; ++r) {
        base[r * INTER + lr]      = acc0[r];
        base[r * INTER + 16 + lr] = acc1[r];
    }
    // Fused quarter sums: s[o][b][q], q = k-octet. 8-lane groups are lr-octets.
    #pragma unroll
    for (int r = 0; r < 4; ++r) {
        float r0 = acc0[r], r1 = acc1[r];
        r0 += __shfl_xor(r0, 1); r0 += __shfl_xor(r0, 2); r0 += __shfl_xor(r0, 4);
        r1 += __shfl_xor(r1, 1); r1 += __shfl_xor(r1, 2); r1 += __shfl_xor(r1, 4);
        if ((lane & 7) == 0) {
            const int b  = m0 + quad * 4 + r;
            const int qq = (lane >> 3) & 1;        // lr 0-7 -> 0, lr 8-15 -> 1
            float* sb = s + ((size_t)(n0 >> 5) * BATCH + b) * 4;
            sb[qq]     = r0;                        // octets 0/1 (k 0..15)
            sb[2 + qq] = r1;                        // octets 2/3 (k 16..31)
        }
    }
}

// ---------------- Branchless screen + survivor list ----------------
// dist >= L = sum_q |s_a,q - s_b,q|. L >= T => term dropped (error <= 512e^-25).
// Loop body = ds_read + 7 VALU + cmp; survivors (expected ~0; diagonal excluded,
// handled as the 1.0 init in prep) append to an LDS list processed after the loop.
// grid (8 ac, 64 o, 2 bs), block 256: a in [ac*64,+64), b in [bs*256,+256), wave w
// covers 64 b's. 1024 blocks = 4/CU = 16 waves/CU.
__global__ __launch_bounds__(256, 4) void screen_kernel(const float* __restrict__ Mt,
                                                        const float* __restrict__ s,
                                                        float* __restrict__ out) {
    const int o    = blockIdx.y;
    const int ac   = blockIdx.x;
    const int bs   = blockIdx.z;
    const int tid  = threadIdx.x;
    const int lane = tid & 63;
    const int wave = tid >> 6;
    const int a    = ac * 64 + lane;
    const float* slabM = Mt + (size_t)o * (BATCH * INTER);
    const float* slabS = s + (size_t)o * (BATCH * 4);

    __shared__ float4 s_lds[256];        // 4 KB: the block's 256 b quarter-sum vectors
    __shared__ unsigned int list[LIST_CAP];
    __shared__ int cnt;
    s_lds[tid] = ((const float4*)slabS)[bs * 256 + tid];
    if (tid == 0) cnt = 0;

    const float4 sa = ((const float4*)slabS)[a];   // coalesced global
    __syncthreads();

    const int b0 = bs * 256 + wave * 64;
    #pragma unroll 8
    for (int j = 0; j < 64; ++j) {
        const float4 sb = s_lds[wave * 64 + j];    // ds_read_b128, wave-uniform broadcast
        const float L = fabsf(sa.x - sb.x) + fabsf(sa.y - sb.y)
                      + fabsf(sa.z - sb.z) + fabsf(sa.w - sb.w);
        const int b = b0 + j;
        if (L < SCREEN_T && b != a) {              // ~never taken: append only
            const int idx = atomicAdd(&cnt, 1);
            if (idx < LIST_CAP) list[idx] = ((unsigned)lane << 16) | (unsigned)b;
        }
    }
    __syncthreads();

    const int n = min(cnt, LIST_CAP);
    for (int i = tid; i < n; i += 256) {           // expected n == 0
        const unsigned v = list[i];
        const int aa = ac * 64 + (int)(v >> 16);
        const int bb = (int)(v & 0xffffu);
        const float* pa = slabM + (size_t)aa * INTER;
        const float* pb = slabM + (size_t)bb * INTER;
        float d0 = 0.f, d1 = 0.f, d2 = 0.f, d3 = 0.f;
        #pragma unroll
        for (int k = 0; k < INTER; k += 4) {
            const float4 va = *(const float4*)(pa + k);
            const float4 vb = *(const float4*)(pb + k);
            d0 += fabsf(va.x - vb.x);
            d1 += fabsf(va.y - vb.y);
            d2 += fabsf(va.z - vb.z);
            d3 += fabsf(va.w - vb.w);
        }
        atomicAdd(&out[(size_t)aa * OUT_W + IN_F + o], __expf(-((d0 + d1) + (d2 + d3))));
    }
}

extern "C" void kernel_launch(void* const* d_in, const int* in_sizes, int n_in,
                              void* d_out, int out_size, void* d_ws, size_t ws_size,
                              hipStream_t stream) {
    const float* x = (const float*)d_in[0];   // [512,1024] fp32
    const float* T = (const float*)d_in[1];   // [1024,2048] fp32 row-major (k-major)
    float* out = (float*)d_out;               // [512,1088] fp32

    // ws layout: xb (1MB) | Bt (4MB) | Mt (4MB f32) | s (512KB) = 9.5MB
    unsigned short* xb = (unsigned short*)d_ws;                          // [512][1024] bf16
    unsigned short* Bt = (unsigned short*)((char*)d_ws + (1u << 20));    // [2048][1024] bf16
    float*          Mt = (float*)((char*)d_ws + (5u << 20));             // [64][512][32] f32
    float*          s  = (float*)((char*)d_ws + (9u << 20));             // [64][512][4] f32

    prep_kernel<<<1024, 256, 0, stream>>>(x, T, out, xb, Bt);

    dim3 ggrid(NCOL / 32, BATCH / 128);       // 64 n-tiles x 4 m-tiles = 256 blocks, 1/CU
    gemm_kernel<<<ggrid, 512, 0, stream>>>(xb, Bt, Mt, s);

    dim3 sgrid(BATCH / 64, OUT_F, 2);         // 1024 blocks, 4/CU
    screen_kernel<<<sgrid, 256, 0, stream>>>(Mt, s, out);
}